// Round 1
// baseline (229.917 us; speedup 1.0000x reference)
//
#include <hip/hip_runtime.h>
#include <cmath>

#define NL 512
#define SS 10
#define DD 128
#define HWC (128 * 128)

typedef short bf16x8 __attribute__((ext_vector_type(8)));
typedef float f32x4 __attribute__((ext_vector_type(4)));

__device__ __forceinline__ void gload_lds16(const void* g, void* l)
{
    __builtin_amdgcn_global_load_lds(
        (__attribute__((address_space(1))) void*)const_cast<void*>(g),
        (__attribute__((address_space(3))) void*)l, 16, 0, 0);
}

// ---------------- transpose (D, HW) -> (HW, D), both images ----------------
__global__ __launch_bounds__(256) void transpose_kernel(
    const float* __restrict__ in1, const float* __restrict__ in2,
    float* __restrict__ out1, float* __restrict__ out2)
{
    const float* in = blockIdx.z ? in2 : in1;
    float* out = blockIdx.z ? out2 : out1;
    __shared__ float tile[32][33];
    int hw0 = blockIdx.x * 32;
    int d0 = blockIdx.y * 32;
    int tx = threadIdx.x, ty = threadIdx.y;  // 32 x 8
#pragma unroll
    for (int j = 0; j < 32; j += 8)
        tile[ty + j][tx] = in[(size_t)(d0 + ty + j) * HWC + hw0 + tx];
    __syncthreads();
#pragma unroll
    for (int j = 0; j < 32; j += 8)
        out[(size_t)(hw0 + ty + j) * DD + d0 + tx] = tile[tx][ty + j];
}

// ---------------- sample points + bilinear + normalize + bf16x3 split ------
__device__ __forceinline__ float fetchd(const float* __restrict__ dt, int y, int x, int d)
{
    bool inb = (x >= 0) && (x < 128) && (y >= 0) && (y < 128);
    int yc = y < 0 ? 0 : (y > 127 ? 127 : y);
    int xc = x < 0 ? 0 : (x > 127 ? 127 : x);
    float v = dt[((size_t)(yc * 128 + xc)) * DD + d];
    return inb ? v : 0.0f;
}

__global__ __launch_bounds__(128) void sample_kernel(
    const float* __restrict__ seg1, const float* __restrict__ seg2,
    const float* __restrict__ dt1, const float* __restrict__ dt2,
    float* __restrict__ dd1, float* __restrict__ dd2,
    unsigned short* __restrict__ h1, unsigned short* __restrict__ m1, unsigned short* __restrict__ l1,
    unsigned short* __restrict__ h2, unsigned short* __restrict__ m2, unsigned short* __restrict__ l2,
    int* __restrict__ v1, int* __restrict__ v2)
{
#pragma clang fp contract(off)
    int L = blockIdx.x;
    int img = blockIdx.y;
    const float* seg = img ? seg2 : seg1;
    const float* dt = img ? dt2 : dt1;
    float* dd = img ? dd2 : dd1;
    unsigned short* ph = img ? h2 : h1;
    unsigned short* pmm = img ? m2 : m1;
    unsigned short* plo = img ? l2 : l1;
    int* vv = img ? v2 : v1;

    float p0y = seg[L * 4 + 0], p0x = seg[L * 4 + 1];
    float p1y = seg[L * 4 + 2], p1x = seg[L * 4 + 3];
    float dy = p0y - p1y, dx = p0x - p1x;
    float len = sqrtf(dy * dy + dx * dx);
    float nf = floorf(len / 8.0f);
    nf = fminf(fmaxf(nf, 2.0f), 10.0f);
    int ni = (int)nf;
    float ivy = (p1y - p0y) / (nf - 1.0f);
    float ivx = (p1x - p0x) / (nf - 1.0f);

    int d = threadIdx.x;
    __shared__ float red[128];

    for (int t = 0; t < SS; ++t) {
        int pt = L * SS + t;
        bool val = t < ni;  // block-uniform
        float outv = 0.0f;
        if (val) {
            float py = p0y + (float)t * ivy;
            float px = p0x + (float)t * ivx;
            float gx = 2.0f * px / 511.0f - 1.0f;
            float gy = 2.0f * py / 511.0f - 1.0f;
            float ix = ((gx + 1.0f) * 128.0f - 1.0f) / 2.0f;
            float iy = ((gy + 1.0f) * 128.0f - 1.0f) / 2.0f;
            float x0f = floorf(ix), y0f = floorf(iy);
            float wx = ix - x0f, wy = iy - y0f;
            int x0 = (int)x0f, y0 = (int)y0f;
            float g00 = fetchd(dt, y0, x0, d);
            float g01 = fetchd(dt, y0, x0 + 1, d);
            float g10 = fetchd(dt, y0 + 1, x0, d);
            float g11 = fetchd(dt, y0 + 1, x0 + 1, d);
            float omwx = 1.0f - wx, omwy = 1.0f - wy;
            float v = g00 * omwy * omwx + g01 * omwy * wx + g10 * wy * omwx + g11 * wy * wx;
            red[d] = v * v;
            __syncthreads();
            for (int s = 64; s > 0; s >>= 1) {
                if (d < s) red[d] += red[d + s];
                __syncthreads();
            }
            float nrm = sqrtf(red[0]);
            outv = v / fmaxf(nrm, 1e-12f);
        }
        dd[(size_t)pt * DD + d] = outv;
        // exact 3-way bf16 split (truncation): outv = h + m + l + O(2^-24 * outv)
        unsigned ub = __float_as_uint(outv);
        unsigned hb = ub & 0xffff0000u;
        float r1 = outv - __uint_as_float(hb);            // exact
        unsigned mb = __float_as_uint(r1) & 0xffff0000u;
        float r2 = r1 - __uint_as_float(mb);              // exact
        unsigned lb = __float_as_uint(r2) & 0xffff0000u;
        // fragment-major layout: [p>>4][k>>3][p&15][k&7]
        int po = ((pt >> 4) << 11) + ((d >> 3) << 7) + ((pt & 15) << 3) + (d & 7);
        ph[po] = (unsigned short)(hb >> 16);
        pmm[po] = (unsigned short)(mb >> 16);
        plo[po] = (unsigned short)(lb >> 16);
        if (d == 0) vv[pt] = val ? 1 : 0;
        __syncthreads();
    }
}

// ---------------- bf16x3 MFMA GEMM (16x16 lines per block) + fused line-score ----
// scores = D1 . D2^T emulated as hh + hm + mh + hl + lh + mm  (error ~2^-27 rel)
__global__ __launch_bounds__(256, 2) void gemm_ls_kernel(
    const unsigned short* __restrict__ ah_, const unsigned short* __restrict__ am_,
    const unsigned short* __restrict__ al_,
    const unsigned short* __restrict__ bh_, const unsigned short* __restrict__ bm_,
    const unsigned short* __restrict__ bl_,
    const int* __restrict__ v1, const int* __restrict__ v2,
    float* __restrict__ ls)
{
    __shared__ __align__(16) char smem[61440];  // 60 KB: staging / epilogue scratch
    int tid = threadIdx.x;
    int wave = tid >> 6, lane = tid & 63;
    int wr = wave >> 1, wc = wave & 1;

    // XCD-aware swizzle (1024 % 8 == 0 -> bijective)
    int flat = blockIdx.y * 32 + blockIdx.x;
    int swz = (flat & 7) * 128 + (flat >> 3);
    int bi = swz >> 5, bj = swz & 31;

    f32x4 zz = {0.0f, 0.0f, 0.0f, 0.0f};
    f32x4 acc[5][5];
#pragma unroll
    for (int i = 0; i < 5; ++i)
#pragma unroll
        for (int j = 0; j < 5; ++j) acc[i][j] = zz;

    for (int ks = 0; ks < 4; ++ks) {
        __syncthreads();
        // stage 60 chunks of 1 KB: A planes h,m,l (10 KB each) then B planes
#pragma unroll
        for (int it = 0; it < 15; ++it) {
            int c = it * 4 + wave;                       // wave-uniform chunk id
            int side = (c >= 30) ? 1 : 0;
            int cc = c - side * 30;
            int plane = cc / 10;
            int pbl = cc - plane * 10;
            const unsigned short* base =
                side ? (plane == 0 ? bh_ : (plane == 1 ? bm_ : bl_))
                     : (plane == 0 ? ah_ : (plane == 1 ? am_ : al_));
            int pb = (side ? bj : bi) * 10 + pbl;
            const unsigned short* gp = base + ((size_t)pb << 11) + (ks << 9) + (lane << 3);
            gload_lds16(gp, &smem[c << 10]);
        }
        asm volatile("s_waitcnt vmcnt(0)" ::: "memory");
        __syncthreads();

        // B fragments for this wave's 5 col-tiles, all 3 planes (conflict-free b128)
        bf16x8 b0[5], b1[5], b2[5];
#pragma unroll
        for (int j = 0; j < 5; ++j) {
            int off = 30720 + ((wc * 5 + j) << 10) + (lane << 4);
            b0[j] = *(const bf16x8*)&smem[off];
            b1[j] = *(const bf16x8*)&smem[off + 10240];
            b2[j] = *(const bf16x8*)&smem[off + 20480];
        }
#pragma unroll
        for (int i = 0; i < 5; ++i) {
            int aoff = ((wr * 5 + i) << 10) + (lane << 4);
            bf16x8 fh = *(const bf16x8*)&smem[aoff];
            bf16x8 fm = *(const bf16x8*)&smem[aoff + 10240];
            bf16x8 fl = *(const bf16x8*)&smem[aoff + 20480];
#pragma unroll
            for (int j = 0; j < 5; ++j) {
                f32x4 t = acc[i][j];
                t = __builtin_amdgcn_mfma_f32_16x16x32_bf16(fh, b0[j], t, 0, 0, 0);
                t = __builtin_amdgcn_mfma_f32_16x16x32_bf16(fh, b1[j], t, 0, 0, 0);
                t = __builtin_amdgcn_mfma_f32_16x16x32_bf16(fm, b0[j], t, 0, 0, 0);
                t = __builtin_amdgcn_mfma_f32_16x16x32_bf16(fh, b2[j], t, 0, 0, 0);
                t = __builtin_amdgcn_mfma_f32_16x16x32_bf16(fl, b0[j], t, 0, 0, 0);
                t = __builtin_amdgcn_mfma_f32_16x16x32_bf16(fm, b1[j], t, 0, 0, 0);
                acc[i][j] = t;
            }
        }
    }

    // ---- fused line-score epilogue: two halves (waves wr==0, then wr==1) ----
    float* scr = (float*)smem;
    for (int half = 0; half < 2; ++half) {
        __syncthreads();
        if (wr == half) {
            float* reg = scr + wc * 6464;  // 64 pairs * 101 floats, per wave
            // scatter C fragments into pair-major layout (pitch 101: odd -> bank-clean reads)
#pragma unroll
            for (int i = 0; i < 5; ++i)
#pragma unroll
                for (int j = 0; j < 5; ++j)
#pragma unroll
                    for (int r = 0; r < 4; ++r) {
                        int row = i * 16 + ((lane >> 4) << 2) + r;  // 0..79 (C: row=(l>>4)*4+reg)
                        int col = j * 16 + (lane & 15);             // 0..79 (C: col=l&15)
                        int pi = row / 10, s = row - pi * 10;
                        int pj = col / 10, t = col - pj * 10;
                        reg[(pi * 8 + pj) * 101 + s * 10 + t] = acc[i][j][r];
                    }
            asm volatile("s_waitcnt lgkmcnt(0)" ::: "memory");
            // one lane owns one 10x10 line-pair (pair index == lane)
            const float* mp = reg + lane * 101;
            int iL = bi * 16 + half * 8 + (lane >> 3);
            int jL = bj * 16 + wc * 8 + (lane & 7);
            int va[10], vb[10];
#pragma unroll
            for (int s = 0; s < 10; ++s) va[s] = v1[iL * 10 + s];
#pragma unroll
            for (int t = 0; t < 10; ++t) vb[t] = v2[jL * 10 + t];
            float cmx[10];
#pragma unroll
            for (int t = 0; t < 10; ++t) cmx[t] = -3.0e38f;
            float sum1 = 0.0f; int c1 = 0;
#pragma unroll
            for (int s = 0; s < 10; ++s) {
                float rmx = -3.0e38f;
#pragma unroll
                for (int t = 0; t < 10; ++t) {
                    float v = (va[s] && vb[t]) ? mp[s * 10 + t] : -1.0f;
                    rmx = fmaxf(rmx, v);
                    cmx[t] = fmaxf(cmx[t], v);
                }
                if (rmx != -1.0f) { sum1 += rmx; c1++; }
            }
            float sum2 = 0.0f; int c2 = 0;
#pragma unroll
            for (int t = 0; t < 10; ++t) {
                if (cmx[t] != -1.0f) { sum2 += cmx[t]; c2++; }
            }
            ls[(size_t)iL * NL + jL] = (sum1 / (float)c1 + sum2 / (float)c2) * 0.5f;
        }
    }
}

// ---------------- top-10: one wave per (line, dir), repeated max-extraction ------
__global__ __launch_bounds__(64) void topk_kernel(
    const float* __restrict__ ls, int* __restrict__ topk)
{
    int i = blockIdx.x;
    int dir = blockIdx.y;
    int lane = threadIdx.x;

    float v[8];
#pragma unroll
    for (int it = 0; it < 8; ++it) {
        int j = it * 64 + lane;
        v[it] = dir ? ls[(size_t)j * NL + i] : ls[(size_t)i * NL + j];
    }
    int* outp = &topk[(size_t)(dir * NL + i) * 10];

    for (int p = 9; p >= 0; --p) {
        float bv = -3.0e38f;
        int bi = -1;
#pragma unroll
        for (int it = 0; it < 8; ++it) {
            int j = it * 64 + lane;
            bool better = (v[it] > bv) || (v[it] == bv && j > bi);
            if (better) { bv = v[it]; bi = j; }
        }
#pragma unroll
        for (int m = 1; m < 64; m <<= 1) {
            float ov = __shfl_xor(bv, m);
            int oi = __shfl_xor(bi, m);
            bool better = (ov > bv) || (ov == bv && oi > bi);
            if (better) { bv = ov; bi = oi; }
        }
        if ((bi & 63) == lane) v[bi >> 6] = -3.0e38f;
        if (lane == 0) outp[p] = bi;
    }
}

// ---------------- Needleman-Wunsch on 10x10 blocks of top-10 candidates ----------
__global__ __launch_bounds__(128) void nw_kernel(
    const float* __restrict__ d1, const float* __restrict__ d2,
    const int* __restrict__ v1, const int* __restrict__ v2,
    const int* __restrict__ topk, float* __restrict__ nwout)
{
    int L = blockIdx.x;
    int dir = blockIdx.y;
    const float* Ad = dir ? d2 : d1;
    const float* Bd = dir ? d1 : d2;
    const int* vA = dir ? v2 : v1;
    const int* vB = dir ? v1 : v2;
    const int* tk = topk + (size_t)(dir * NL + L) * 10;

    __shared__ float Asl[10 * 132];
    __shared__ float Bsl[10 * 132];
    __shared__ float M[10][110];  // [cand][s*11+t]
    __shared__ int vam[10];

    int tid = threadIdx.x;
#pragma unroll
    for (int it = 0; it < 10; ++it) {
        int idx = tid + it * 128;
        int row = idx >> 7, col = idx & 127;
        Asl[row * 132 + col] = Ad[((size_t)L * 10 + row) * DD + col];
    }
    if (tid < 10) vam[tid] = vA[L * 10 + tid];

    for (int c = 0; c < 10; ++c) {
        int j = tk[c];
        __syncthreads();
#pragma unroll
        for (int it = 0; it < 10; ++it) {
            int idx = tid + it * 128;
            int row = idx >> 7, col = idx & 127;
            Bsl[row * 132 + col] = Bd[((size_t)j * 10 + row) * DD + col];
        }
        __syncthreads();
        if (tid < 100) {
            int s = tid / 10, t = tid - s * 10;
            const float4* ap = (const float4*)&Asl[s * 132];
            const float4* bp = (const float4*)&Bsl[t * 132];
            float acc = 0.0f;
#pragma unroll
            for (int k = 0; k < 32; ++k) {
                float4 a = ap[k], b = bp[k];
                acc = fmaf(a.x, b.x, acc);
                acc = fmaf(a.y, b.y, acc);
                acc = fmaf(a.z, b.z, acc);
                acc = fmaf(a.w, b.w, acc);
            }
            int ok = vam[s] && vB[j * 10 + t];
            M[c][s * 11 + t] = ok ? acc : -1.0f;
        }
    }
    __syncthreads();

    if (tid < 20) {
        int c = tid % 10, f = tid / 10;
        float prev[11];
#pragma unroll
        for (int p = 0; p < 11; ++p) prev[p] = 0.0f;
#pragma unroll
        for (int s = 0; s < 10; ++s) {
            float oldp = prev[0];
            float run = -3.0e38f;
#pragma unroll
            for (int t = 0; t < 10; ++t) {
                int tt = f ? (9 - t) : t;
                float sc = M[c][s * 11 + tt] - 0.1f;
                float pt1 = prev[t + 1];
                float av = fmaxf(pt1, oldp + sc);
                run = fmaxf(run, av);
                prev[t + 1] = fmaxf(run, 0.0f);
                oldp = pt1;
            }
        }
        nwout[((size_t)(dir * NL + L)) * 20 + f * 10 + c] = prev[10];
    }
}

// ---------------- argmax + mutual check ----------------
__global__ __launch_bounds__(512) void final_kernel(
    const float* __restrict__ nw, const int* __restrict__ topk, int* __restrict__ out)
{
    __shared__ int m1[NL], m2[NL];
    int t = threadIdx.x;
    {
        const float* p = nw + (size_t)t * 20;
        float bb = -3.0e38f; int kk = 0;
        for (int k = 0; k < 20; ++k) {
            float v = p[k];
            if (v > bb) { bb = v; kk = k; }
        }
        m1[t] = topk[(size_t)t * 10 + (kk % 10)];
    }
    {
        const float* p = nw + (size_t)(NL + t) * 20;
        float bb = -3.0e38f; int kk = 0;
        for (int k = 0; k < 20; ++k) {
            float v = p[k];
            if (v > bb) { bb = v; kk = k; }
        }
        m2[t] = topk[(size_t)(NL + t) * 10 + (kk % 10)];
    }
    __syncthreads();
    int mt = m1[t];
    out[t] = (m2[mt] == t) ? mt : -1;
}

extern "C" void kernel_launch(void* const* d_in, const int* in_sizes, int n_in,
                              void* d_out, int out_size, void* d_ws, size_t ws_size,
                              hipStream_t stream)
{
    const float* seg1 = (const float*)d_in[0];
    const float* seg2 = (const float*)d_in[1];
    const float* desc1 = (const float*)d_in[2];
    const float* desc2 = (const float*)d_in[3];
    int* out = (int*)d_out;

    char* ws = (char*)d_ws;
    size_t off = 0;
    float* dt1 = (float*)(ws + off); off += (size_t)DD * HWC * 4;        // 8 MB
    float* dt2 = (float*)(ws + off); off += (size_t)DD * HWC * 4;        // 8 MB
    float* dd1 = (float*)(ws + off); off += (size_t)NL * SS * DD * 4;    // 2.5 MB
    float* dd2 = (float*)(ws + off); off += (size_t)NL * SS * DD * 4;    // 2.5 MB
    int* v1 = (int*)(ws + off); off += (size_t)NL * SS * 4;
    int* v2 = (int*)(ws + off); off += (size_t)NL * SS * 4;
    float* ls = (float*)(ws + off); off += (size_t)NL * NL * 4;          // 1 MB
    int* topk = (int*)(ws + off); off += (size_t)2 * NL * 10 * 4;
    float* nwv = (float*)(ws + off); off += (size_t)2 * NL * 20 * 4;
    size_t PL = (size_t)NL * SS * DD;                                    // 655360 elems
    unsigned short* h1 = (unsigned short*)(ws + off); off += PL * 2;     // 1.25 MB each
    unsigned short* m1 = (unsigned short*)(ws + off); off += PL * 2;
    unsigned short* l1 = (unsigned short*)(ws + off); off += PL * 2;
    unsigned short* h2 = (unsigned short*)(ws + off); off += PL * 2;
    unsigned short* m2 = (unsigned short*)(ws + off); off += PL * 2;
    unsigned short* l2 = (unsigned short*)(ws + off); off += PL * 2;

    transpose_kernel<<<dim3(HWC / 32, DD / 32, 2), dim3(32, 8), 0, stream>>>(
        desc1, desc2, dt1, dt2);
    sample_kernel<<<dim3(NL, 2), 128, 0, stream>>>(
        seg1, seg2, dt1, dt2, dd1, dd2, h1, m1, l1, h2, m2, l2, v1, v2);
    gemm_ls_kernel<<<dim3(32, 32), 256, 0, stream>>>(
        h1, m1, l1, h2, m2, l2, v1, v2, ls);
    topk_kernel<<<dim3(NL, 2), 64, 0, stream>>>(ls, topk);
    nw_kernel<<<dim3(NL, 2), 128, 0, stream>>>(dd1, dd2, v1, v2, topk, nwv);
    final_kernel<<<1, 512, 0, stream>>>(nwv, topk, out);
}